// Round 12
// baseline (3853.675 us; speedup 1.0000x reference)
//
#include <hip/hip_runtime.h>

// LSTMFromEmbeddings: B=128, T=1024, E=256, H=256, C=2, bidirectional + meanpool + linear.
//
// R12 = dual-chain interleave over the proven R8 step (1941us kernel), 1 barrier/step.
//  rec: 32 persistent wgs; wg = member m (0..3) of chain pair {(d,2p),(d,2p+1)}.
//       Weights (member's 64 units, R8 col mapping) in registers, shared by chains.
//       Iteration (2 steps, 2 lgkm-only barriers):
//         gloads x_{t+2} (A,B) | hhA -> gLa | hhB -> gLb | bar1 |
//         ewA, pubA (coalesced R8 mapping) | ewB, pubB | xgA | xgB |
//         pollA (late; batched parallel retry) -> HSa | pollB -> HSb | bar2
//       Each chain's publish->poll exchange RT hides under the other chain's work.
//  prep: bf16(x*mask) image in LDS-tile layout (gload_lds staging, 2 steps ahead).
//  head: out = (hsum/1024) @ W_lin^T + b_lin.

#define B_ 128
#define T_ 1024
#define E_ 256
#define H_ 256

typedef short short8 __attribute__((ext_vector_type(8)));
typedef float f32x4 __attribute__((ext_vector_type(4)));
typedef float f32x2 __attribute__((ext_vector_type(2)));

__device__ __forceinline__ unsigned short f2bf(float f) {
  unsigned u = __builtin_bit_cast(unsigned, f);
  u += 0x7fffu + ((u >> 16) & 1u);  // RNE
  return (unsigned short)(u >> 16);
}
__device__ __forceinline__ f32x4 mfma16(short8 a, short8 b, f32x4 c) {
  return __builtin_amdgcn_mfma_f32_16x16x32_bf16(a, b, c, 0, 0, 0);
}
__device__ __forceinline__ float rcpf(float x) { return __builtin_amdgcn_rcpf(x); }

// proven R8 elementwise: 5 exp + 3 rcp per unit
__device__ __forceinline__ float lstm_ew(float gi, float gf, float gg, float go, float& c) {
  float ei = __expf(-gi), ef = __expf(-gf), eg = __expf(-2.f * gg);
  float di = 1.f + ei, df = 1.f + ef, dg = 1.f + eg;
  float r1 = rcpf(di * dg);
  float si = r1 * dg;
  float tg = 2.f * (r1 * di) - 1.f;
  c = rcpf(df) * c + si * tg;
  float eo = __expf(-go), ec = __expf(2.f * c);
  float do_ = 1.f + eo, dc = 1.f + ec;
  float r3 = rcpf(do_ * dc);
  float so = r3 * dc;
  float th = 1.f - 2.f * (r3 * do_);
  return so * th;
}

__device__ __forceinline__ short8 cvt8(f32x4 v0, f32x4 v1) {
  short8 o;
  o[0] = (short)f2bf(v0[0]); o[1] = (short)f2bf(v0[1]);
  o[2] = (short)f2bf(v0[2]); o[3] = (short)f2bf(v0[3]);
  o[4] = (short)f2bf(v1[0]); o[5] = (short)f2bf(v1[1]);
  o[6] = (short)f2bf(v1[2]); o[7] = (short)f2bf(v1[3]);
  return o;
}

__device__ __forceinline__ void bar_lds() {  // LDS-only barrier; vmem stays in flight
  asm volatile("s_waitcnt lgkmcnt(0)" ::: "memory");
  __builtin_amdgcn_s_barrier();
}

__device__ __forceinline__ void gload16(const void* g, void* l) {
  __builtin_amdgcn_global_load_lds(
      (const __attribute__((address_space(1))) void*)g,
      (__attribute__((address_space(3))) void*)l, 16, 0, 0);
}

// ---------------- prep: x image in LDS-tile layout ---------------------------
__global__ __launch_bounds__(256, 4) void prep_kernel(
    const float* __restrict__ x, const float* __restrict__ mask,
    unsigned short* __restrict__ img) {
  int gid = blockIdx.x * 256 + threadIdx.x;
  int i = gid & 511;
  int tt = (gid >> 9) & 1023;
  int bblk = gid >> 19;
  int r = i >> 5, s = i & 31, kc = s ^ (r & 7);
  int b = bblk * 16 + r;
  const f32x4* src = (const f32x4*)(x + ((size_t)b * T_ + tt) * E_ + kc * 8);
  float mk = mask[(size_t)b * T_ + tt];
  ((short8*)img)[gid] = cvt8(src[0] * mk, src[1] * mk);
}

// ---------------- rec: dual-chain fused projection + recurrence ---------------
// grid 32, 512 threads. g8 = bid & 7 -> (d = g8>>2, p = g8&3); m = bid >> 3.
// Chains: A = (d, bblk 2p), B = (d, bblk 2p+1). Members co-XCD (bids mod 8 equal).
template <bool PREP>
__global__ __launch_bounds__(512, 1) void rec_kernel(
    const float* __restrict__ x, const float* __restrict__ mask,
    const unsigned short* __restrict__ img,
    const float* __restrict__ WihF, const float* __restrict__ WhhF,
    const float* __restrict__ bF, const float* __restrict__ WihB,
    const float* __restrict__ WhhB, const float* __restrict__ bB,
    unsigned long long* __restrict__ Hbuf, float* __restrict__ hsum) {
  __shared__ __align__(16) short XSa[2][16 * 256], XSb[2][16 * 256];  // 32KB
  __shared__ __align__(16) short HSa[2][16 * 256], HSb[2][16 * 256];  // 32KB
  __shared__ __align__(16) float gLa[16 * 260], gLb[16 * 260];        // 33.3KB

  const int bid = blockIdx.x;
  const int g8 = bid & 7, m = bid >> 3;
  const int d = g8 >> 2, p = g8 & 3;
  const int bblkA = 2 * p, bblkB = 2 * p + 1;
  const int gA = d * 8 + bblkA, gB = d * 8 + bblkB;
  const int tid = threadIdx.x;
  const int w = tid >> 6, l = tid & 63, l15 = l & 15, l4 = l >> 4;
  const int sr = tid >> 5, sc = tid & 31;
  const int ej2 = sc * 2;
  const int gbA = bblkA * 16 + sr, gbB = bblkB * 16 + sr;

  const float* Wih = d ? WihB : WihF;
  const float* Whh = d ? WhhB : WhhF;
  const float* bias = d ? bB : bF;

  // ---- weight fragments -> registers (R8 col mapping; shared by both chains) --
  short8 wi[2][8], wh[2][8];
  float biasv[2];
#pragma unroll
  for (int i = 0; i < 2; ++i) {
    int cp = (2 * w + i) * 16 + l15;   // col' 0..255
    int gate = cp >> 6, ul = cp & 63;
    size_t nat = (size_t)(gate * 256 + m * 64 + ul);
    biasv[i] = bias[nat];
#pragma unroll
    for (int kb = 0; kb < 8; ++kb) {
      const f32x4* pi = (const f32x4*)(Wih + nat * E_ + kb * 32 + l4 * 8);
      wi[i][kb] = cvt8(pi[0], pi[1]);
      const f32x4* ph = (const f32x4*)(Whh + nat * H_ + kb * 32 + l4 * 8);
      wh[i][kb] = cvt8(ph[0], ph[1]);
    }
  }
  const int ub = m * 64 + ej2;

  // x image source pointers; one 8KB tile per t
  const int dstep = d ? -8192 : 8192;
  const char* gsrcA = (const char*)img +
      ((size_t)(bblkA * 1024 + (d ? (T_ - 1) : 0)) * 8192) + (size_t)tid * 16;
  const char* gsrcB = (const char*)img +
      ((size_t)(bblkB * 1024 + (d ? (T_ - 1) : 0)) * 8192) + (size_t)tid * 16;

  // ---- prologue: zero HS parity-0; stage x_0,x_1 both chains; acc = bias+xg_0 --
  ((int4*)HSa)[tid] = (int4){0, 0, 0, 0};
  ((int4*)HSb)[tid] = (int4){0, 0, 0, 0};
  if constexpr (PREP) {
    gload16(gsrcA, (char*)XSa[0] + w * 1024);
    gload16(gsrcA + dstep, (char*)XSa[1] + w * 1024);
    gsrcA += 2 * dstep;
    gload16(gsrcB, (char*)XSb[0] + w * 1024);
    gload16(gsrcB + dstep, (char*)XSb[1] + w * 1024);
    gsrcB += 2 * dstep;
  } else {
    int ts = d ? (T_ - 1) : 0;
    const f32x4* pa = (const f32x4*)(x + ((size_t)gbA * T_ + ts) * E_ + sc * 8);
    float ma = mask[(size_t)gbA * T_ + ts];
    ((short8*)XSa[0])[sr * 32 + (sc ^ (sr & 7))] = cvt8(pa[0] * ma, pa[1] * ma);
    const f32x4* pb = (const f32x4*)(x + ((size_t)gbB * T_ + ts) * E_ + sc * 8);
    float mb = mask[(size_t)gbB * T_ + ts];
    ((short8*)XSb[0])[sr * 32 + (sc ^ (sr & 7))] = cvt8(pb[0] * mb, pb[1] * mb);
  }
  __syncthreads();  // drains gloads + HS zeros visible

  f32x4 acA[2], acA2[2], acB[2], acB2[2];
#pragma unroll
  for (int i = 0; i < 2; ++i) {
    acA[i] = (f32x4){biasv[i], biasv[i], biasv[i], biasv[i]};
    acB[i] = acA[i];
    acA2[i] = (f32x4){0.f, 0.f, 0.f, 0.f};
    acB2[i] = acA2[i];
  }
#pragma unroll
  for (int kp = 0; kp < 4; ++kp) {
    short8 a0 = ((short8*)XSa[0])[l15 * 32 + ((kp * 8 + l4) ^ (l15 & 7))];
    short8 a1 = ((short8*)XSa[0])[l15 * 32 + ((kp * 8 + 4 + l4) ^ (l15 & 7))];
    acA[0] = mfma16(a0, wi[0][2 * kp], acA[0]);
    acA[1] = mfma16(a0, wi[1][2 * kp], acA[1]);
    acA2[0] = mfma16(a1, wi[0][2 * kp + 1], acA2[0]);
    acA2[1] = mfma16(a1, wi[1][2 * kp + 1], acA2[1]);
    short8 b0 = ((short8*)XSb[0])[l15 * 32 + ((kp * 8 + l4) ^ (l15 & 7))];
    short8 b1 = ((short8*)XSb[0])[l15 * 32 + ((kp * 8 + 4 + l4) ^ (l15 & 7))];
    acB[0] = mfma16(b0, wi[0][2 * kp], acB[0]);
    acB[1] = mfma16(b0, wi[1][2 * kp], acB[1]);
    acB2[0] = mfma16(b1, wi[0][2 * kp + 1], acB2[0]);
    acB2[1] = mfma16(b1, wi[1][2 * kp + 1], acB2[1]);
  }
  __syncthreads();  // XS*[0] consumed before first in-loop gload overwrites

  float csA[2] = {0.f, 0.f}, hsA[2] = {0.f, 0.f};
  float csB[2] = {0.f, 0.f}, hsB[2] = {0.f, 0.f};

  for (int t = 0; t < T_; ++t) {
    const bool more = (t + 1 < T_);

    // gloads x_{t+2} (A,B): retired by this iter's poll vmcnt (in-order) + bar2
    if constexpr (PREP) {
      if (t + 2 < T_) {
        gload16(gsrcA, (char*)XSa[t & 1] + w * 1024);
        gsrcA += dstep;
        gload16(gsrcB, (char*)XSb[t & 1] + w * 1024);
        gsrcB += dstep;
      }
    }
    f32x4 xa0, xa1, xb0, xb1;
    float mka = 0.f, mkb = 0.f;
    if constexpr (!PREP) {
      if (more) {
        int ts = d ? (T_ - 2 - t) : (t + 1);
        const f32x4* pa = (const f32x4*)(x + ((size_t)gbA * T_ + ts) * E_ + sc * 8);
        xa0 = pa[0]; xa1 = pa[1];
        mka = mask[(size_t)gbA * T_ + ts];
        const f32x4* pb = (const f32x4*)(x + ((size_t)gbB * T_ + ts) * E_ + sc * 8);
        xb0 = pb[0]; xb1 = pb[1];
        mkb = mask[(size_t)gbB * T_ + ts];
      }
    }

    // hhA -> gLa
    {
      const short8* hsP = (const short8*)HSa[t & 1];
#pragma unroll
      for (int kp = 0; kp < 4; ++kp) {
        short8 a0 = hsP[l15 * 32 + ((kp * 8 + l4) ^ (l15 & 7))];
        short8 a1 = hsP[l15 * 32 + ((kp * 8 + 4 + l4) ^ (l15 & 7))];
        acA[0] = mfma16(a0, wh[0][2 * kp], acA[0]);
        acA[1] = mfma16(a0, wh[1][2 * kp], acA[1]);
        acA2[0] = mfma16(a1, wh[0][2 * kp + 1], acA2[0]);
        acA2[1] = mfma16(a1, wh[1][2 * kp + 1], acA2[1]);
      }
#pragma unroll
      for (int i = 0; i < 2; ++i)
#pragma unroll
        for (int r = 0; r < 4; ++r)
          gLa[(l4 * 4 + r) * 260 + (2 * w + i) * 16 + l15] = acA[i][r] + acA2[i][r];
    }
    // hhB -> gLb
    {
      const short8* hsP = (const short8*)HSb[t & 1];
#pragma unroll
      for (int kp = 0; kp < 4; ++kp) {
        short8 a0 = hsP[l15 * 32 + ((kp * 8 + l4) ^ (l15 & 7))];
        short8 a1 = hsP[l15 * 32 + ((kp * 8 + 4 + l4) ^ (l15 & 7))];
        acB[0] = mfma16(a0, wh[0][2 * kp], acB[0]);
        acB[1] = mfma16(a0, wh[1][2 * kp], acB[1]);
        acB2[0] = mfma16(a1, wh[0][2 * kp + 1], acB2[0]);
        acB2[1] = mfma16(a1, wh[1][2 * kp + 1], acB2[1]);
      }
#pragma unroll
      for (int i = 0; i < 2; ++i)
#pragma unroll
        for (int r = 0; r < 4; ++r)
          gLb[(l4 * 4 + r) * 260 + (2 * w + i) * 16 + l15] = acB[i][r] + acB2[i][r];
    }
    if constexpr (!PREP) {
      if (more) {
        ((short8*)XSa[(t + 1) & 1])[sr * 32 + (sc ^ (sr & 7))] = cvt8(xa0 * mka, xa1 * mka);
        ((short8*)XSb[(t + 1) & 1])[sr * 32 + (sc ^ (sr & 7))] = cvt8(xb0 * mkb, xb1 * mkb);
      }
    }
    bar_lds();  // bar1: gLa, gLb (and fallback XS) visible

    const unsigned tag = (unsigned)(t + 1);
    const size_t baseA = ((size_t)gA * 2 + (tag & 1)) * 16;
    const size_t baseB = ((size_t)gB * 2 + (tag & 1)) * 16;

    // ewA + publish A (coalesced R8 mapping)
    float hA0, hA1;
    {
      const float* gp = &gLa[sr * 260 + ej2];
      hA0 = lstm_ew(gp[0], gp[64], gp[128], gp[192], csA[0]);
      hA1 = lstm_ew(gp[1], gp[65], gp[129], gp[193], csA[1]);
      hsA[0] += hA0; hsA[1] += hA1;
      if (more) {
        unsigned pay;
        asm("v_cvt_pk_bf16_f32 %0, %1, %2" : "=v"(pay) : "v"(hA0), "v"(hA1));
        unsigned long long word = (((unsigned long long)tag) << 32) | (unsigned long long)pay;
        __hip_atomic_store(&Hbuf[(baseA + sr) * 128 + m * 32 + sc], word,
                           __ATOMIC_RELAXED, __HIP_MEMORY_SCOPE_AGENT);
        asm volatile("" ::: "memory");
      }
    }
    // ewB + publish B
    float hB0, hB1;
    {
      const float* gp = &gLb[sr * 260 + ej2];
      hB0 = lstm_ew(gp[0], gp[64], gp[128], gp[192], csB[0]);
      hB1 = lstm_ew(gp[1], gp[65], gp[129], gp[193], csB[1]);
      hsB[0] += hB0; hsB[1] += hB1;
      if (more) {
        unsigned pay;
        asm("v_cvt_pk_bf16_f32 %0, %1, %2" : "=v"(pay) : "v"(hB0), "v"(hB1));
        unsigned long long word = (((unsigned long long)tag) << 32) | (unsigned long long)pay;
        __hip_atomic_store(&Hbuf[(baseB + sr) * 128 + m * 32 + sc], word,
                           __ATOMIC_RELAXED, __HIP_MEMORY_SCOPE_AGENT);
        asm volatile("" ::: "memory");
      }
    }

    if (more) {
      // xgA, xgB: acc = bias + xg_{t+1} (hides publish propagation)
#pragma unroll
      for (int i = 0; i < 2; ++i) {
        acA[i] = (f32x4){biasv[i], biasv[i], biasv[i], biasv[i]};
        acB[i] = acA[i];
        acA2[i] = (f32x4){0.f, 0.f, 0.f, 0.f};
        acB2[i] = acA2[i];
      }
      const short8* xna = (const short8*)XSa[(t + 1) & 1];
      const short8* xnb = (const short8*)XSb[(t + 1) & 1];
#pragma unroll
      for (int kp = 0; kp < 4; ++kp) {
        short8 a0 = xna[l15 * 32 + ((kp * 8 + l4) ^ (l15 & 7))];
        short8 a1 = xna[l15 * 32 + ((kp * 8 + 4 + l4) ^ (l15 & 7))];
        acA[0] = mfma16(a0, wi[0][2 * kp], acA[0]);
        acA[1] = mfma16(a0, wi[1][2 * kp], acA[1]);
        acA2[0] = mfma16(a1, wi[0][2 * kp + 1], acA2[0]);
        acA2[1] = mfma16(a1, wi[1][2 * kp + 1], acA2[1]);
      }
#pragma unroll
      for (int kp = 0; kp < 4; ++kp) {
        short8 b0 = xnb[l15 * 32 + ((kp * 8 + l4) ^ (l15 & 7))];
        short8 b1 = xnb[l15 * 32 + ((kp * 8 + 4 + l4) ^ (l15 & 7))];
        acB[0] = mfma16(b0, wi[0][2 * kp], acB[0]);
        acB[1] = mfma16(b0, wi[1][2 * kp], acB[1]);
        acB2[0] = mfma16(b1, wi[0][2 * kp + 1], acB2[0]);
        acB2[1] = mfma16(b1, wi[1][2 * kp + 1], acB2[1]);
      }

      // poll A (late; batched parallel retry) -> HSa[(t+1)&1]
      {
        const unsigned long long* rp = &Hbuf[(baseA + sr) * 128 + sc * 4];
        unsigned long long vv[4];
#pragma unroll
        for (int j = 0; j < 4; ++j)
          vv[j] = __hip_atomic_load(&rp[j], __ATOMIC_RELAXED, __HIP_MEMORY_SCOPE_AGENT);
        asm volatile("" ::: "memory");
        for (;;) {
          bool ok = true;
#pragma unroll
          for (int j = 0; j < 4; ++j) ok &= ((unsigned)(vv[j] >> 32) == tag);
          if (ok) break;
#pragma unroll
          for (int j = 0; j < 4; ++j)
            if ((unsigned)(vv[j] >> 32) != tag)
              vv[j] = __hip_atomic_load(&rp[j], __ATOMIC_RELAXED, __HIP_MEMORY_SCOPE_AGENT);
          asm volatile("" ::: "memory");
        }
        int4 hw;
        hw.x = (int)(unsigned)vv[0]; hw.y = (int)(unsigned)vv[1];
        hw.z = (int)(unsigned)vv[2]; hw.w = (int)(unsigned)vv[3];
        *(int4*)((char*)HSa[(t + 1) & 1] + (size_t)(sr * 32 + (sc ^ (sr & 7))) * 16) = hw;
      }
      // poll B -> HSb[(t+1)&1]
      {
        const unsigned long long* rp = &Hbuf[(baseB + sr) * 128 + sc * 4];
        unsigned long long vv[4];
#pragma unroll
        for (int j = 0; j < 4; ++j)
          vv[j] = __hip_atomic_load(&rp[j], __ATOMIC_RELAXED, __HIP_MEMORY_SCOPE_AGENT);
        asm volatile("" ::: "memory");
        for (;;) {
          bool ok = true;
#pragma unroll
          for (int j = 0; j < 4; ++j) ok &= ((unsigned)(vv[j] >> 32) == tag);
          if (ok) break;
#pragma unroll
          for (int j = 0; j < 4; ++j)
            if ((unsigned)(vv[j] >> 32) != tag)
              vv[j] = __hip_atomic_load(&rp[j], __ATOMIC_RELAXED, __HIP_MEMORY_SCOPE_AGENT);
          asm volatile("" ::: "memory");
        }
        int4 hw;
        hw.x = (int)(unsigned)vv[0]; hw.y = (int)(unsigned)vv[1];
        hw.z = (int)(unsigned)vv[2]; hw.w = (int)(unsigned)vv[3];
        *(int4*)((char*)HSb[(t + 1) & 1] + (size_t)(sr * 32 + (sc ^ (sr & 7))) * 16) = hw;
      }
      bar_lds();  // bar2: HS visible; XS/gL reads done
    }
  }

  // pooled sums (disjoint slots per thread per chain)
  *(f32x2*)(hsum + ((size_t)d * B_ + gbA) * H_ + ub) = (f32x2){hsA[0], hsA[1]};
  *(f32x2*)(hsum + ((size_t)d * B_ + gbB) * H_ + ub) = (f32x2){hsB[0], hsB[1]};
}

// ---------------- head: linear ----------------------------------------------
__global__ __launch_bounds__(256, 1) void head_kernel(
    const float* __restrict__ hsum, const float* __restrict__ Wlin,
    const float* __restrict__ blin, float* __restrict__ out) {
  int tid = threadIdx.x;  // 256 = 128 b x 2 c
  int b = tid >> 1, c = tid & 1;
  const f32x4* hf = (const f32x4*)(hsum + (size_t)b * H_);
  const f32x4* hbk = (const f32x4*)(hsum + (size_t)B_ * H_ + (size_t)b * H_);
  const f32x4* wl = (const f32x4*)(Wlin + (size_t)c * 512);
  float s = 0.f;
  for (int j = 0; j < 64; ++j) {
    f32x4 a = hf[j], ww = wl[j];
    s += a[0] * ww[0] + a[1] * ww[1] + a[2] * ww[2] + a[3] * ww[3];
  }
  for (int j = 0; j < 64; ++j) {
    f32x4 a = hbk[j], ww = wl[64 + j];
    s += a[0] * ww[0] + a[1] * ww[1] + a[2] * ww[2] + a[3] * ww[3];
  }
  out[tid] = s * (1.0f / 1024.0f) + blin[c];
}

// ---------------- launch -----------------------------------------------------
extern "C" void kernel_launch(void* const* d_in, const int* in_sizes, int n_in,
                              void* d_out, int out_size, void* d_ws, size_t ws_size,
                              hipStream_t stream) {
  const float* emb = (const float*)d_in[0];
  const float* mask = (const float*)d_in[1];
  const float* Wih_f = (const float*)d_in[2];
  const float* Whh_f = (const float*)d_in[3];
  const float* b_f = (const float*)d_in[4];
  const float* Wih_b = (const float*)d_in[5];
  const float* Whh_b = (const float*)d_in[6];
  const float* b_b = (const float*)d_in[7];
  const float* Wlin = (const float*)d_in[8];
  const float* blin = (const float*)d_in[9];
  float* out = (float*)d_out;

  const size_t HBUF_BYTES = (size_t)16 * 2 * 16 * 128 * 8;  // 512 KiB
  const size_t HSUM_BYTES = (size_t)2 * B_ * H_ * 4;        // 256 KiB
  const size_t IMG_BYTES = (size_t)8 * 1024 * 512 * 16;     // 64 MiB
  if (ws_size < HBUF_BYTES + HSUM_BYTES) return;
  const bool prep = ws_size >= HBUF_BYTES + HSUM_BYTES + IMG_BYTES;

  char* ws = (char*)d_ws;
  unsigned long long* Hbuf = (unsigned long long*)ws;
  float* hsum = (float*)(ws + HBUF_BYTES);
  unsigned short* img = (unsigned short*)(ws + HBUF_BYTES + HSUM_BYTES);

  (void)hipMemsetAsync(Hbuf, 0, HBUF_BYTES, stream);  // tags start at 1; replay-safe
  if (prep) {
    prep_kernel<<<16384, 256, 0, stream>>>(emb, mask, img);
    rec_kernel<true><<<32, 512, 0, stream>>>(emb, mask, img, Wih_f, Whh_f, b_f,
                                             Wih_b, Whh_b, b_b, Hbuf, hsum);
  } else {
    rec_kernel<false><<<32, 512, 0, stream>>>(emb, mask, img, Wih_f, Whh_f, b_f,
                                              Wih_b, Whh_b, b_b, Hbuf, hsum);
  }
  head_kernel<<<1, 256, 0, stream>>>(hsum, Wlin, blin, out);
}

// Round 13
// 1672.396 us; speedup vs baseline: 2.3043x; 2.3043x over previous
//
#include <hip/hip_runtime.h>

// LSTMFromEmbeddings: B=128, T=1024, E=256, H=256, C=2, bidirectional + meanpool + linear.
//
// R13: transposed MFMA (weights = A operand, h/x = B operand) + weight ROW permutation
// so D[row=4q+gate][col=batch] puts all 4 gates of one (batch,unit) in ONE lane's acc.
// Deletes the gates-LDS round trip and one barrier (1 lgkm barrier/step). Publish stays
// coalesced via batch-minor Hbuf words (contiguous 512B per wave). Sync protocol
// (tagged parity words, late poll, batched retry) identical to the passing R8.
//  rec: 64 wgs = 16 groups (2 dir x 8 batch-blocks of 16) x 4 members (64 units).
//  prep: bf16(x*mask) image in LDS-tile layout (gload_lds staging, 2 steps ahead).
//  head: out = (hsum/1024) @ W_lin^T + b_lin.

#define B_ 128
#define T_ 1024
#define E_ 256
#define H_ 256

typedef short short8 __attribute__((ext_vector_type(8)));
typedef float f32x4 __attribute__((ext_vector_type(4)));
typedef float f32x2 __attribute__((ext_vector_type(2)));

__device__ __forceinline__ unsigned short f2bf(float f) {
  unsigned u = __builtin_bit_cast(unsigned, f);
  u += 0x7fffu + ((u >> 16) & 1u);  // RNE
  return (unsigned short)(u >> 16);
}
__device__ __forceinline__ f32x4 mfma16(short8 a, short8 b, f32x4 c) {
  return __builtin_amdgcn_mfma_f32_16x16x32_bf16(a, b, c, 0, 0, 0);
}
__device__ __forceinline__ float rcpf(float x) { return __builtin_amdgcn_rcpf(x); }

// proven R8 elementwise: 5 exp + 3 rcp per unit
__device__ __forceinline__ float lstm_ew(float gi, float gf, float gg, float go, float& c) {
  float ei = __expf(-gi), ef = __expf(-gf), eg = __expf(-2.f * gg);
  float di = 1.f + ei, df = 1.f + ef, dg = 1.f + eg;
  float r1 = rcpf(di * dg);
  float si = r1 * dg;
  float tg = 2.f * (r1 * di) - 1.f;
  c = rcpf(df) * c + si * tg;
  float eo = __expf(-go), ec = __expf(2.f * c);
  float do_ = 1.f + eo, dc = 1.f + ec;
  float r3 = rcpf(do_ * dc);
  float so = r3 * dc;
  float th = 1.f - 2.f * (r3 * do_);
  return so * th;
}

__device__ __forceinline__ short8 cvt8(f32x4 v0, f32x4 v1) {
  short8 o;
  o[0] = (short)f2bf(v0[0]); o[1] = (short)f2bf(v0[1]);
  o[2] = (short)f2bf(v0[2]); o[3] = (short)f2bf(v0[3]);
  o[4] = (short)f2bf(v1[0]); o[5] = (short)f2bf(v1[1]);
  o[6] = (short)f2bf(v1[2]); o[7] = (short)f2bf(v1[3]);
  return o;
}

__device__ __forceinline__ void bar_lds() {  // LDS-only barrier; vmem stays in flight
  asm volatile("s_waitcnt lgkmcnt(0)" ::: "memory");
  __builtin_amdgcn_s_barrier();
}

__device__ __forceinline__ void gload16(const void* g, void* l) {
  __builtin_amdgcn_global_load_lds(
      (const __attribute__((address_space(1))) void*)g,
      (__attribute__((address_space(3))) void*)l, 16, 0, 0);
}

// ---------------- prep: x image in LDS-tile layout ---------------------------
__global__ __launch_bounds__(256, 4) void prep_kernel(
    const float* __restrict__ x, const float* __restrict__ mask,
    unsigned short* __restrict__ img) {
  int gid = blockIdx.x * 256 + threadIdx.x;
  int i = gid & 511;
  int tt = (gid >> 9) & 1023;
  int bblk = gid >> 19;
  int r = i >> 5, s = i & 31, kc = s ^ (r & 7);
  int b = bblk * 16 + r;
  const f32x4* src = (const f32x4*)(x + ((size_t)b * T_ + tt) * E_ + kc * 8);
  float mk = mask[(size_t)b * T_ + tt];
  ((short8*)img)[gid] = cvt8(src[0] * mk, src[1] * mk);
}

// ---------------- rec: fused projection + recurrence --------------------------
// grid 64, 512 threads. g = bid & 15, m = bid >> 4. Member m owns units [m*64,+64).
// A-operand (weights) row map: tile T = 2w+i; row rho = l15: gate = rho&3,
//   unit = w*8 + (rho>>2)*2 + i.  D: col = l15 (batch), row = l4*4+r ->
//   lane's acc[i][r] = gate r of unit (w*8 + l4*2 + i), batch l15.
template <bool PREP>
__global__ __launch_bounds__(512, 1) void rec_kernel(
    const float* __restrict__ x, const float* __restrict__ mask,
    const unsigned short* __restrict__ img,
    const float* __restrict__ WihF, const float* __restrict__ WhhF,
    const float* __restrict__ bF, const float* __restrict__ WihB,
    const float* __restrict__ WhhB, const float* __restrict__ bB,
    unsigned long long* __restrict__ Hbuf, float* __restrict__ hsum) {
  __shared__ __align__(16) short XS[2][16 * 256];  // x stage, parity dbuf (16KB)
  __shared__ __align__(16) short HS[2][16 * 256];  // h stage, parity dbuf (16KB)

  const int bid = blockIdx.x;
  const int g = bid & 15, m = bid >> 4;
  const int d = g >> 3, bblk = g & 7;
  const int tid = threadIdx.x;
  const int w = tid >> 6, l = tid & 63, l15 = l & 15, l4 = l >> 4;
  const int sr = tid >> 5, sc = tid & 31;  // fallback staging row/chunk
  const int gb_s = bblk * 16 + sr;

  const float* Wih = d ? WihB : WihF;
  const float* Whh = d ? WhhB : WhhF;
  const float* bias = d ? bB : bF;

  // ---- weight A-fragments -> registers ----
  short8 wi[2][8], wh[2][8];
#pragma unroll
  for (int i = 0; i < 2; ++i) {
    int u_row = w * 8 + (l15 >> 2) * 2 + i;           // unit of this A row
    size_t nat = (size_t)((l15 & 3) * 256 + m * 64 + u_row);
#pragma unroll
    for (int kb = 0; kb < 8; ++kb) {
      const f32x4* pi = (const f32x4*)(Wih + nat * E_ + kb * 32 + l4 * 8);
      wi[i][kb] = cvt8(pi[0], pi[1]);
      const f32x4* ph = (const f32x4*)(Whh + nat * H_ + kb * 32 + l4 * 8);
      wh[i][kb] = cvt8(ph[0], ph[1]);
    }
  }
  // bias for D-side (lane's own units): acc[i][r] = gate r of unit w*8+l4*2+i
  f32x4 bias4[2];
#pragma unroll
  for (int i = 0; i < 2; ++i)
#pragma unroll
    for (int r = 0; r < 4; ++r)
      bias4[i][r] = bias[r * 256 + m * 64 + w * 8 + l4 * 2 + i];

  // x image source pointer; one 8KB tile per t
  const int dstep = d ? -8192 : 8192;
  const char* gsrc = (const char*)img +
      ((size_t)(bblk * 1024 + (d ? (T_ - 1) : 0)) * 8192) + (size_t)tid * 16;

  // ---- prologue: HS[0]=0; stage x_0 (and x_1); acc = bias + xg_0 ----
  ((int4*)HS)[tid] = (int4){0, 0, 0, 0};  // zeros HS[0]
  if constexpr (PREP) {
    gload16(gsrc, (char*)XS[0] + w * 1024);
    gload16(gsrc + dstep, (char*)XS[1] + w * 1024);
    gsrc += 2 * dstep;
  } else {
    int ts = d ? (T_ - 1) : 0;
    const f32x4* px = (const f32x4*)(x + ((size_t)gb_s * T_ + ts) * E_ + sc * 8);
    float mk = mask[(size_t)gb_s * T_ + ts];
    ((short8*)XS[0])[sr * 32 + (sc ^ (sr & 7))] = cvt8(px[0] * mk, px[1] * mk);
  }
  __syncthreads();  // drains gloads + HS[0] zeros visible

  f32x4 acc[2], accB[2];
  acc[0] = bias4[0];
  acc[1] = bias4[1];
  accB[0] = (f32x4){0.f, 0.f, 0.f, 0.f};
  accB[1] = (f32x4){0.f, 0.f, 0.f, 0.f};
#pragma unroll
  for (int kp = 0; kp < 4; ++kp) {
    short8 b0 = ((short8*)XS[0])[l15 * 32 + ((kp * 8 + l4) ^ (l15 & 7))];
    short8 b1 = ((short8*)XS[0])[l15 * 32 + ((kp * 8 + 4 + l4) ^ (l15 & 7))];
    acc[0] = mfma16(wi[0][2 * kp], b0, acc[0]);
    acc[1] = mfma16(wi[1][2 * kp], b0, acc[1]);
    accB[0] = mfma16(wi[0][2 * kp + 1], b1, accB[0]);
    accB[1] = mfma16(wi[1][2 * kp + 1], b1, accB[1]);
  }
  __syncthreads();  // XS[0] consumed before first in-loop gload overwrites it

  float cs[2] = {0.f, 0.f};
  float hsums[2] = {0.f, 0.f};

  for (int t = 0; t < T_; ++t) {
    const bool more = (t + 1 < T_);

    if constexpr (PREP) {
      if (t + 2 < T_) {  // stage x_{t+2}; retired by this step's poll vmcnt + barrier
        gload16(gsrc, (char*)XS[t & 1] + w * 1024);
        gsrc += dstep;
      }
    }
    f32x4 xv0, xv1;
    float mk = 0.f;
    if constexpr (!PREP) {
      if (more) {
        int ts = d ? (T_ - 2 - t) : (t + 1);
        const f32x4* px = (const f32x4*)(x + ((size_t)gb_s * T_ + ts) * E_ + sc * 8);
        xv0 = px[0]; xv1 = px[1];
        mk = mask[(size_t)gb_s * T_ + ts];
      }
    }

    // hh product into acc (acc holds bias + xg_t); HS[t&1] holds h_t (zeros at t=0)
    {
      const short8* hsP = (const short8*)HS[t & 1];
#pragma unroll
      for (int kp = 0; kp < 4; ++kp) {
        short8 b0 = hsP[l15 * 32 + ((kp * 8 + l4) ^ (l15 & 7))];
        short8 b1 = hsP[l15 * 32 + ((kp * 8 + 4 + l4) ^ (l15 & 7))];
        acc[0] = mfma16(wh[0][2 * kp], b0, acc[0]);
        acc[1] = mfma16(wh[1][2 * kp], b0, acc[1]);
        accB[0] = mfma16(wh[0][2 * kp + 1], b1, accB[0]);
        accB[1] = mfma16(wh[1][2 * kp + 1], b1, accB[1]);
      }
    }

    // ew DIRECTLY on acc (gates r = i,f,g,o of unit w*8+l4*2+i, batch l15)
    float h0 = lstm_ew(acc[0][0] + accB[0][0], acc[0][1] + accB[0][1],
                       acc[0][2] + accB[0][2], acc[0][3] + accB[0][3], cs[0]);
    float h1 = lstm_ew(acc[1][0] + accB[1][0], acc[1][1] + accB[1][1],
                       acc[1][2] + accB[1][2], acc[1][3] + accB[1][3], cs[1]);
    hsums[0] += h0;
    hsums[1] += h1;

    if (more) {
      const unsigned tag = (unsigned)(t + 1);
      const size_t base = ((size_t)g * 2 + (tag & 1)) * 2048;  // [grp][par][128uw][16b]

      // publish: 1 word, units (u, u+1), u = m*64 + w*8 + l4*2; uw = m*32+w*4+l4.
      // Hbuf word = uw*16 + batch -> wave stores contiguous (lane = l4*16+l15).
      unsigned pay;
      asm("v_cvt_pk_bf16_f32 %0, %1, %2" : "=v"(pay) : "v"(h0), "v"(h1));
      unsigned long long word = (((unsigned long long)tag) << 32) | (unsigned long long)pay;
      __hip_atomic_store(&Hbuf[base + (size_t)((m * 32 + w * 4 + l4) * 16 + l15)], word,
                         __ATOMIC_RELAXED, __HIP_MEMORY_SCOPE_AGENT);
      asm volatile("" ::: "memory");  // publish before polls

      // own HS slice: units (u,u+1) of batch l15 -> one b32 (chunk c = m*8+w)
      {
        int c_own = m * 8 + w;
        *(int*)((char*)HS[(t + 1) & 1] +
                (size_t)(l15 * 512 + ((c_own ^ (l15 & 7)) << 4) + l4 * 4)) = (int)pay;
      }

      if constexpr (!PREP) {
        ((short8*)XS[(t + 1) & 1])[sr * 32 + (sc ^ (sr & 7))] = cvt8(xv0 * mk, xv1 * mk);
        bar_lds();  // XS visible (PREP: staged 2 steps ago, already guaranteed)
      }

      // acc = bias + xg_{t+1} (fills publish->visibility window)
      acc[0] = bias4[0];
      acc[1] = bias4[1];
      accB[0] = (f32x4){0.f, 0.f, 0.f, 0.f};
      accB[1] = (f32x4){0.f, 0.f, 0.f, 0.f};
      const short8* xsN = (const short8*)XS[(t + 1) & 1];
#pragma unroll
      for (int kp = 0; kp < 4; ++kp) {
        short8 b0 = xsN[l15 * 32 + ((kp * 8 + l4) ^ (l15 & 7))];
        short8 b1 = xsN[l15 * 32 + ((kp * 8 + 4 + l4) ^ (l15 & 7))];
        acc[0] = mfma16(wi[0][2 * kp], b0, acc[0]);
        acc[1] = mfma16(wi[1][2 * kp], b0, acc[1]);
        accB[0] = mfma16(wi[0][2 * kp + 1], b1, accB[0]);
        accB[1] = mfma16(wi[1][2 * kp + 1], b1, accB[1]);
      }

      // poll peers: 3 contiguous words/thread (skip own member's 512-word block)
      {
        unsigned long long vv[3];
        int phys[3];
#pragma unroll
        for (int j = 0; j < 3; ++j) {
          int p = tid * 3 + j;
          phys[j] = p + (p >= m * 512 ? 512 : 0);
          vv[j] = __hip_atomic_load(&Hbuf[base + phys[j]], __ATOMIC_RELAXED,
                                    __HIP_MEMORY_SCOPE_AGENT);
        }
        asm volatile("" ::: "memory");
        for (;;) {  // batched parallel retry rounds
          bool ok = true;
#pragma unroll
          for (int j = 0; j < 3; ++j) ok &= ((unsigned)(vv[j] >> 32) == tag);
          if (ok) break;
#pragma unroll
          for (int j = 0; j < 3; ++j)
            if ((unsigned)(vv[j] >> 32) != tag)
              vv[j] = __hip_atomic_load(&Hbuf[base + phys[j]], __ATOMIC_RELAXED,
                                        __HIP_MEMORY_SCOPE_AGENT);
          asm volatile("" ::: "memory");
        }
        // unpack: word phys = uw*16 + b -> HS[b][units 2*(uw&31) of member uw>>5]
#pragma unroll
        for (int j = 0; j < 3; ++j) {
          int uw = phys[j] >> 4, b = phys[j] & 15;
          int mm = uw >> 5, q5 = uw & 31;
          int c = mm * 8 + (q5 >> 2);
          *(int*)((char*)HS[(t + 1) & 1] +
                  (size_t)(b * 512 + ((c ^ (b & 7)) << 4) + (q5 & 3) * 4)) =
              (int)(unsigned)vv[j];
        }
      }
      bar_lds();  // HS[(t+1)&1] (own+peers) visible; XS reads done
    }
  }

  // pooled sums: lane owns (batch bblk*16+l15, units gu, gu+1) — 8B store
  {
    int gb_t = bblk * 16 + l15;
    int gu = m * 64 + w * 8 + l4 * 2;
    *(f32x2*)(hsum + ((size_t)d * B_ + gb_t) * H_ + gu) = (f32x2){hsums[0], hsums[1]};
  }
}

// ---------------- head: linear ----------------------------------------------
__global__ __launch_bounds__(256, 1) void head_kernel(
    const float* __restrict__ hsum, const float* __restrict__ Wlin,
    const float* __restrict__ blin, float* __restrict__ out) {
  int tid = threadIdx.x;  // 256 = 128 b x 2 c
  int b = tid >> 1, c = tid & 1;
  const f32x4* hf = (const f32x4*)(hsum + (size_t)b * H_);
  const f32x4* hbk = (const f32x4*)(hsum + (size_t)B_ * H_ + (size_t)b * H_);
  const f32x4* wl = (const f32x4*)(Wlin + (size_t)c * 512);
  float s = 0.f;
  for (int j = 0; j < 64; ++j) {
    f32x4 a = hf[j], ww = wl[j];
    s += a[0] * ww[0] + a[1] * ww[1] + a[2] * ww[2] + a[3] * ww[3];
  }
  for (int j = 0; j < 64; ++j) {
    f32x4 a = hbk[j], ww = wl[64 + j];
    s += a[0] * ww[0] + a[1] * ww[1] + a[2] * ww[2] + a[3] * ww[3];
  }
  out[tid] = s * (1.0f / 1024.0f) + blin[c];
}

// ---------------- launch -----------------------------------------------------
extern "C" void kernel_launch(void* const* d_in, const int* in_sizes, int n_in,
                              void* d_out, int out_size, void* d_ws, size_t ws_size,
                              hipStream_t stream) {
  const float* emb = (const float*)d_in[0];
  const float* mask = (const float*)d_in[1];
  const float* Wih_f = (const float*)d_in[2];
  const float* Whh_f = (const float*)d_in[3];
  const float* b_f = (const float*)d_in[4];
  const float* Wih_b = (const float*)d_in[5];
  const float* Whh_b = (const float*)d_in[6];
  const float* b_b = (const float*)d_in[7];
  const float* Wlin = (const float*)d_in[8];
  const float* blin = (const float*)d_in[9];
  float* out = (float*)d_out;

  const size_t HBUF_BYTES = (size_t)16 * 2 * 2048 * 8;      // 512 KiB
  const size_t HSUM_BYTES = (size_t)2 * B_ * H_ * 4;        // 256 KiB
  const size_t IMG_BYTES = (size_t)8 * 1024 * 512 * 16;     // 64 MiB
  if (ws_size < HBUF_BYTES + HSUM_BYTES) return;
  const bool prep = ws_size >= HBUF_BYTES + HSUM_BYTES + IMG_BYTES;

  char* ws = (char*)d_ws;
  unsigned long long* Hbuf = (unsigned long long*)ws;
  float* hsum = (float*)(ws + HBUF_BYTES);
  unsigned short* img = (unsigned short*)(ws + HBUF_BYTES + HSUM_BYTES);

  (void)hipMemsetAsync(Hbuf, 0, HBUF_BYTES, stream);  // tags start at 1; replay-safe
  if (prep) {
    prep_kernel<<<16384, 256, 0, stream>>>(emb, mask, img);
    rec_kernel<true><<<64, 512, 0, stream>>>(emb, mask, img, Wih_f, Whh_f, b_f,
                                             Wih_b, Whh_b, b_b, Hbuf, hsum);
  } else {
    rec_kernel<false><<<64, 512, 0, stream>>>(emb, mask, img, Wih_f, Whh_f, b_f,
                                              Wih_b, Whh_b, b_b, Hbuf, hsum);
  }
  head_kernel<<<1, 256, 0, stream>>>(hsum, Wlin, blin, out);
}

// Round 14
// 1668.623 us; speedup vs baseline: 2.3095x; 1.0023x over previous
//
#include <hip/hip_runtime.h>

// LSTMFromEmbeddings: B=128, T=1024, E=256, H=256, C=2, bidirectional + meanpool + linear.
//
// R13: transposed MFMA (weights = A operand, h/x = B operand) + weight ROW permutation
// so D[row=4q+gate][col=batch] puts all 4 gates of one (batch,unit) in ONE lane's acc.
// Deletes the gates-LDS round trip and one barrier (1 lgkm barrier/step). Publish stays
// coalesced via batch-minor Hbuf words (contiguous 512B per wave). Sync protocol
// (tagged parity words, late poll, batched retry) identical to the passing R8.
//  rec: 64 wgs = 16 groups (2 dir x 8 batch-blocks of 16) x 4 members (64 units).
//  prep: bf16(x*mask) image in LDS-tile layout (gload_lds staging, 2 steps ahead).
//  head: out = (hsum/1024) @ W_lin^T + b_lin.

#define B_ 128
#define T_ 1024
#define E_ 256
#define H_ 256

typedef short short8 __attribute__((ext_vector_type(8)));
typedef float f32x4 __attribute__((ext_vector_type(4)));
typedef float f32x2 __attribute__((ext_vector_type(2)));

__device__ __forceinline__ unsigned short f2bf(float f) {
  unsigned u = __builtin_bit_cast(unsigned, f);
  u += 0x7fffu + ((u >> 16) & 1u);  // RNE
  return (unsigned short)(u >> 16);
}
__device__ __forceinline__ f32x4 mfma16(short8 a, short8 b, f32x4 c) {
  return __builtin_amdgcn_mfma_f32_16x16x32_bf16(a, b, c, 0, 0, 0);
}
__device__ __forceinline__ float rcpf(float x) { return __builtin_amdgcn_rcpf(x); }

// proven R8 elementwise: 5 exp + 3 rcp per unit
__device__ __forceinline__ float lstm_ew(float gi, float gf, float gg, float go, float& c) {
  float ei = __expf(-gi), ef = __expf(-gf), eg = __expf(-2.f * gg);
  float di = 1.f + ei, df = 1.f + ef, dg = 1.f + eg;
  float r1 = rcpf(di * dg);
  float si = r1 * dg;
  float tg = 2.f * (r1 * di) - 1.f;
  c = rcpf(df) * c + si * tg;
  float eo = __expf(-go), ec = __expf(2.f * c);
  float do_ = 1.f + eo, dc = 1.f + ec;
  float r3 = rcpf(do_ * dc);
  float so = r3 * dc;
  float th = 1.f - 2.f * (r3 * do_);
  return so * th;
}

__device__ __forceinline__ short8 cvt8(f32x4 v0, f32x4 v1) {
  short8 o;
  o[0] = (short)f2bf(v0[0]); o[1] = (short)f2bf(v0[1]);
  o[2] = (short)f2bf(v0[2]); o[3] = (short)f2bf(v0[3]);
  o[4] = (short)f2bf(v1[0]); o[5] = (short)f2bf(v1[1]);
  o[6] = (short)f2bf(v1[2]); o[7] = (short)f2bf(v1[3]);
  return o;
}

__device__ __forceinline__ void bar_lds() {  // LDS-only barrier; vmem stays in flight
  asm volatile("s_waitcnt lgkmcnt(0)" ::: "memory");
  __builtin_amdgcn_s_barrier();
}

__device__ __forceinline__ void gload16(const void* g, void* l) {
  __builtin_amdgcn_global_load_lds(
      (const __attribute__((address_space(1))) void*)g,
      (__attribute__((address_space(3))) void*)l, 16, 0, 0);
}

// ---------------- prep: x image in LDS-tile layout ---------------------------
__global__ __launch_bounds__(256, 4) void prep_kernel(
    const float* __restrict__ x, const float* __restrict__ mask,
    unsigned short* __restrict__ img) {
  int gid = blockIdx.x * 256 + threadIdx.x;
  int i = gid & 511;
  int tt = (gid >> 9) & 1023;
  int bblk = gid >> 19;
  int r = i >> 5, s = i & 31, kc = s ^ (r & 7);
  int b = bblk * 16 + r;
  const f32x4* src = (const f32x4*)(x + ((size_t)b * T_ + tt) * E_ + kc * 8);
  float mk = mask[(size_t)b * T_ + tt];
  ((short8*)img)[gid] = cvt8(src[0] * mk, src[1] * mk);
}

// ---------------- rec: fused projection + recurrence --------------------------
// grid 64, 512 threads. g = bid & 15, m = bid >> 4. Member m owns units [m*64,+64).
// A-operand (weights) row map: tile T = 2w+i; row rho = l15: gate = rho&3,
//   unit = w*8 + (rho>>2)*2 + i.  D: col = l15 (batch), row = l4*4+r ->
//   lane's acc[i][r] = gate r of unit (w*8 + l4*2 + i), batch l15.
template <bool PREP>
__global__ __launch_bounds__(512, 1) void rec_kernel(
    const float* __restrict__ x, const float* __restrict__ mask,
    const unsigned short* __restrict__ img,
    const float* __restrict__ WihF, const float* __restrict__ WhhF,
    const float* __restrict__ bF, const float* __restrict__ WihB,
    const float* __restrict__ WhhB, const float* __restrict__ bB,
    unsigned long long* __restrict__ Hbuf, float* __restrict__ hsum) {
  __shared__ __align__(16) short XS[2][16 * 256];  // x stage, parity dbuf (16KB)
  __shared__ __align__(16) short HS[2][16 * 256];  // h stage, parity dbuf (16KB)

  const int bid = blockIdx.x;
  const int g = bid & 15, m = bid >> 4;
  const int d = g >> 3, bblk = g & 7;
  const int tid = threadIdx.x;
  const int w = tid >> 6, l = tid & 63, l15 = l & 15, l4 = l >> 4;
  const int sr = tid >> 5, sc = tid & 31;  // fallback staging row/chunk
  const int gb_s = bblk * 16 + sr;

  const float* Wih = d ? WihB : WihF;
  const float* Whh = d ? WhhB : WhhF;
  const float* bias = d ? bB : bF;

  // ---- weight A-fragments -> registers ----
  short8 wi[2][8], wh[2][8];
#pragma unroll
  for (int i = 0; i < 2; ++i) {
    int u_row = w * 8 + (l15 >> 2) * 2 + i;           // unit of this A row
    size_t nat = (size_t)((l15 & 3) * 256 + m * 64 + u_row);
#pragma unroll
    for (int kb = 0; kb < 8; ++kb) {
      const f32x4* pi = (const f32x4*)(Wih + nat * E_ + kb * 32 + l4 * 8);
      wi[i][kb] = cvt8(pi[0], pi[1]);
      const f32x4* ph = (const f32x4*)(Whh + nat * H_ + kb * 32 + l4 * 8);
      wh[i][kb] = cvt8(ph[0], ph[1]);
    }
  }
  // bias for D-side (lane's own units): acc[i][r] = gate r of unit w*8+l4*2+i
  f32x4 bias4[2];
#pragma unroll
  for (int i = 0; i < 2; ++i)
#pragma unroll
    for (int r = 0; r < 4; ++r)
      bias4[i][r] = bias[r * 256 + m * 64 + w * 8 + l4 * 2 + i];

  // x image source pointer; one 8KB tile per t
  const int dstep = d ? -8192 : 8192;
  const char* gsrc = (const char*)img +
      ((size_t)(bblk * 1024 + (d ? (T_ - 1) : 0)) * 8192) + (size_t)tid * 16;

  // ---- prologue: HS[0]=0; stage x_0 (and x_1); acc = bias + xg_0 ----
  ((int4*)HS)[tid] = (int4){0, 0, 0, 0};  // zeros HS[0]
  if constexpr (PREP) {
    gload16(gsrc, (char*)XS[0] + w * 1024);
    gload16(gsrc + dstep, (char*)XS[1] + w * 1024);
    gsrc += 2 * dstep;
  } else {
    int ts = d ? (T_ - 1) : 0;
    const f32x4* px = (const f32x4*)(x + ((size_t)gb_s * T_ + ts) * E_ + sc * 8);
    float mk = mask[(size_t)gb_s * T_ + ts];
    ((short8*)XS[0])[sr * 32 + (sc ^ (sr & 7))] = cvt8(px[0] * mk, px[1] * mk);
  }
  __syncthreads();  // drains gloads + HS[0] zeros visible

  f32x4 acc[2], accB[2];
  acc[0] = bias4[0];
  acc[1] = bias4[1];
  accB[0] = (f32x4){0.f, 0.f, 0.f, 0.f};
  accB[1] = (f32x4){0.f, 0.f, 0.f, 0.f};
#pragma unroll
  for (int kp = 0; kp < 4; ++kp) {
    short8 b0 = ((short8*)XS[0])[l15 * 32 + ((kp * 8 + l4) ^ (l15 & 7))];
    short8 b1 = ((short8*)XS[0])[l15 * 32 + ((kp * 8 + 4 + l4) ^ (l15 & 7))];
    acc[0] = mfma16(wi[0][2 * kp], b0, acc[0]);
    acc[1] = mfma16(wi[1][2 * kp], b0, acc[1]);
    accB[0] = mfma16(wi[0][2 * kp + 1], b1, accB[0]);
    accB[1] = mfma16(wi[1][2 * kp + 1], b1, accB[1]);
  }
  __syncthreads();  // XS[0] consumed before first in-loop gload overwrites it

  float cs[2] = {0.f, 0.f};
  float hsums[2] = {0.f, 0.f};

  for (int t = 0; t < T_; ++t) {
    const bool more = (t + 1 < T_);

    if constexpr (PREP) {
      if (t + 2 < T_) {  // stage x_{t+2}; retired by this step's poll vmcnt + barrier
        gload16(gsrc, (char*)XS[t & 1] + w * 1024);
        gsrc += dstep;
      }
    }
    f32x4 xv0, xv1;
    float mk = 0.f;
    if constexpr (!PREP) {
      if (more) {
        int ts = d ? (T_ - 2 - t) : (t + 1);
        const f32x4* px = (const f32x4*)(x + ((size_t)gb_s * T_ + ts) * E_ + sc * 8);
        xv0 = px[0]; xv1 = px[1];
        mk = mask[(size_t)gb_s * T_ + ts];
      }
    }

    // hh product into acc (acc holds bias + xg_t); HS[t&1] holds h_t (zeros at t=0)
    {
      const short8* hsP = (const short8*)HS[t & 1];
#pragma unroll
      for (int kp = 0; kp < 4; ++kp) {
        short8 b0 = hsP[l15 * 32 + ((kp * 8 + l4) ^ (l15 & 7))];
        short8 b1 = hsP[l15 * 32 + ((kp * 8 + 4 + l4) ^ (l15 & 7))];
        acc[0] = mfma16(wh[0][2 * kp], b0, acc[0]);
        acc[1] = mfma16(wh[1][2 * kp], b0, acc[1]);
        accB[0] = mfma16(wh[0][2 * kp + 1], b1, accB[0]);
        accB[1] = mfma16(wh[1][2 * kp + 1], b1, accB[1]);
      }
    }

    // ew DIRECTLY on acc (gates r = i,f,g,o of unit w*8+l4*2+i, batch l15)
    float h0 = lstm_ew(acc[0][0] + accB[0][0], acc[0][1] + accB[0][1],
                       acc[0][2] + accB[0][2], acc[0][3] + accB[0][3], cs[0]);
    float h1 = lstm_ew(acc[1][0] + accB[1][0], acc[1][1] + accB[1][1],
                       acc[1][2] + accB[1][2], acc[1][3] + accB[1][3], cs[1]);
    hsums[0] += h0;
    hsums[1] += h1;

    if (more) {
      const unsigned tag = (unsigned)(t + 1);
      const size_t base = ((size_t)g * 2 + (tag & 1)) * 2048;  // [grp][par][128uw][16b]

      // publish: 1 word, units (u, u+1), u = m*64 + w*8 + l4*2; uw = m*32+w*4+l4.
      // Hbuf word = uw*16 + batch -> wave stores contiguous (lane = l4*16+l15).
      unsigned pay;
      asm("v_cvt_pk_bf16_f32 %0, %1, %2" : "=v"(pay) : "v"(h0), "v"(h1));
      unsigned long long word = (((unsigned long long)tag) << 32) | (unsigned long long)pay;
      __hip_atomic_store(&Hbuf[base + (size_t)((m * 32 + w * 4 + l4) * 16 + l15)], word,
                         __ATOMIC_RELAXED, __HIP_MEMORY_SCOPE_AGENT);
      asm volatile("" ::: "memory");  // publish before polls

      // own HS slice: units (u,u+1) of batch l15 -> one b32 (chunk c = m*8+w)
      {
        int c_own = m * 8 + w;
        *(int*)((char*)HS[(t + 1) & 1] +
                (size_t)(l15 * 512 + ((c_own ^ (l15 & 7)) << 4) + l4 * 4)) = (int)pay;
      }

      if constexpr (!PREP) {
        ((short8*)XS[(t + 1) & 1])[sr * 32 + (sc ^ (sr & 7))] = cvt8(xv0 * mk, xv1 * mk);
        bar_lds();  // XS visible (PREP: staged 2 steps ago, already guaranteed)
      }

      // acc = bias + xg_{t+1} (fills publish->visibility window)
      acc[0] = bias4[0];
      acc[1] = bias4[1];
      accB[0] = (f32x4){0.f, 0.f, 0.f, 0.f};
      accB[1] = (f32x4){0.f, 0.f, 0.f, 0.f};
      const short8* xsN = (const short8*)XS[(t + 1) & 1];
#pragma unroll
      for (int kp = 0; kp < 4; ++kp) {
        short8 b0 = xsN[l15 * 32 + ((kp * 8 + l4) ^ (l15 & 7))];
        short8 b1 = xsN[l15 * 32 + ((kp * 8 + 4 + l4) ^ (l15 & 7))];
        acc[0] = mfma16(wi[0][2 * kp], b0, acc[0]);
        acc[1] = mfma16(wi[1][2 * kp], b0, acc[1]);
        accB[0] = mfma16(wi[0][2 * kp + 1], b1, accB[0]);
        accB[1] = mfma16(wi[1][2 * kp + 1], b1, accB[1]);
      }

      // poll peers: 3 contiguous words/thread (skip own member's 512-word block)
      {
        unsigned long long vv[3];
        int phys[3];
#pragma unroll
        for (int j = 0; j < 3; ++j) {
          int p = tid * 3 + j;
          phys[j] = p + (p >= m * 512 ? 512 : 0);
          vv[j] = __hip_atomic_load(&Hbuf[base + phys[j]], __ATOMIC_RELAXED,
                                    __HIP_MEMORY_SCOPE_AGENT);
        }
        asm volatile("" ::: "memory");
        for (;;) {  // batched parallel retry rounds
          bool ok = true;
#pragma unroll
          for (int j = 0; j < 3; ++j) ok &= ((unsigned)(vv[j] >> 32) == tag);
          if (ok) break;
#pragma unroll
          for (int j = 0; j < 3; ++j)
            if ((unsigned)(vv[j] >> 32) != tag)
              vv[j] = __hip_atomic_load(&Hbuf[base + phys[j]], __ATOMIC_RELAXED,
                                        __HIP_MEMORY_SCOPE_AGENT);
          asm volatile("" ::: "memory");
        }
        // unpack: word phys = uw*16 + b -> HS[b][units 2*(uw&31) of member uw>>5]
#pragma unroll
        for (int j = 0; j < 3; ++j) {
          int uw = phys[j] >> 4, b = phys[j] & 15;
          int mm = uw >> 5, q5 = uw & 31;
          int c = mm * 8 + (q5 >> 2);
          *(int*)((char*)HS[(t + 1) & 1] +
                  (size_t)(b * 512 + ((c ^ (b & 7)) << 4) + (q5 & 3) * 4)) =
              (int)(unsigned)vv[j];
        }
      }
      bar_lds();  // HS[(t+1)&1] (own+peers) visible; XS reads done
    }
  }

  // pooled sums: lane owns (batch bblk*16+l15, units gu, gu+1) — 8B store
  {
    int gb_t = bblk * 16 + l15;
    int gu = m * 64 + w * 8 + l4 * 2;
    *(f32x2*)(hsum + ((size_t)d * B_ + gb_t) * H_ + gu) = (f32x2){hsums[0], hsums[1]};
  }
}

// ---------------- head: linear ----------------------------------------------
__global__ __launch_bounds__(256, 1) void head_kernel(
    const float* __restrict__ hsum, const float* __restrict__ Wlin,
    const float* __restrict__ blin, float* __restrict__ out) {
  int tid = threadIdx.x;  // 256 = 128 b x 2 c
  int b = tid >> 1, c = tid & 1;
  const f32x4* hf = (const f32x4*)(hsum + (size_t)b * H_);
  const f32x4* hbk = (const f32x4*)(hsum + (size_t)B_ * H_ + (size_t)b * H_);
  const f32x4* wl = (const f32x4*)(Wlin + (size_t)c * 512);
  float s = 0.f;
  for (int j = 0; j < 64; ++j) {
    f32x4 a = hf[j], ww = wl[j];
    s += a[0] * ww[0] + a[1] * ww[1] + a[2] * ww[2] + a[3] * ww[3];
  }
  for (int j = 0; j < 64; ++j) {
    f32x4 a = hbk[j], ww = wl[64 + j];
    s += a[0] * ww[0] + a[1] * ww[1] + a[2] * ww[2] + a[3] * ww[3];
  }
  out[tid] = s * (1.0f / 1024.0f) + blin[c];
}

// ---------------- launch -----------------------------------------------------
extern "C" void kernel_launch(void* const* d_in, const int* in_sizes, int n_in,
                              void* d_out, int out_size, void* d_ws, size_t ws_size,
                              hipStream_t stream) {
  const float* emb = (const float*)d_in[0];
  const float* mask = (const float*)d_in[1];
  const float* Wih_f = (const float*)d_in[2];
  const float* Whh_f = (const float*)d_in[3];
  const float* b_f = (const float*)d_in[4];
  const float* Wih_b = (const float*)d_in[5];
  const float* Whh_b = (const float*)d_in[6];
  const float* b_b = (const float*)d_in[7];
  const float* Wlin = (const float*)d_in[8];
  const float* blin = (const float*)d_in[9];
  float* out = (float*)d_out;

  const size_t HBUF_BYTES = (size_t)16 * 2 * 2048 * 8;      // 512 KiB
  const size_t HSUM_BYTES = (size_t)2 * B_ * H_ * 4;        // 256 KiB
  const size_t IMG_BYTES = (size_t)8 * 1024 * 512 * 16;     // 64 MiB
  if (ws_size < HBUF_BYTES + HSUM_BYTES) return;
  const bool prep = ws_size >= HBUF_BYTES + HSUM_BYTES + IMG_BYTES;

  char* ws = (char*)d_ws;
  unsigned long long* Hbuf = (unsigned long long*)ws;
  float* hsum = (float*)(ws + HBUF_BYTES);
  unsigned short* img = (unsigned short*)(ws + HBUF_BYTES + HSUM_BYTES);

  (void)hipMemsetAsync(Hbuf, 0, HBUF_BYTES, stream);  // tags start at 1; replay-safe
  if (prep) {
    prep_kernel<<<16384, 256, 0, stream>>>(emb, mask, img);
    rec_kernel<true><<<64, 512, 0, stream>>>(emb, mask, img, Wih_f, Whh_f, b_f,
                                             Wih_b, Whh_b, b_b, Hbuf, hsum);
  } else {
    rec_kernel<false><<<64, 512, 0, stream>>>(emb, mask, img, Wih_f, Whh_f, b_f,
                                              Wih_b, Whh_b, b_b, Hbuf, hsum);
  }
  head_kernel<<<1, 256, 0, stream>>>(hsum, Wlin, blin, out);
}

// Round 15
// 1536.627 us; speedup vs baseline: 2.5079x; 1.0859x over previous
//
#include <hip/hip_runtime.h>

// LSTMFromEmbeddings: B=128, T=1024, E=256, H=256, C=2, bidirectional + meanpool + linear.
//
// R14 = R13 (transposed MFMA, gates in-lane, 1 barrier/step, proven tagged-word sync)
//  + rotation LDS swizzle (c+r)&31  — XOR swizzle collapsed B-operand reads onto 2/8
//    bank groups; rotation spreads 8 lanes/group (b128 minimum)
//  + t-loop unrolled by 2 with compile-time parity — all LDS/Hbuf bases loop-invariant,
//    poll phys indices + unpack offsets precomputed.
//  rec: 64 wgs = 16 groups (2 dir x 8 batch-blocks of 16) x 4 members (64 units).
//  prep: bf16(x*mask) image in LDS-tile layout (rotation swizzle pre-applied).
//  head: out = (hsum/1024) @ W_lin^T + b_lin.

#define B_ 128
#define T_ 1024
#define E_ 256
#define H_ 256

typedef short short8 __attribute__((ext_vector_type(8)));
typedef float f32x4 __attribute__((ext_vector_type(4)));
typedef float f32x2 __attribute__((ext_vector_type(2)));

__device__ __forceinline__ unsigned short f2bf(float f) {
  unsigned u = __builtin_bit_cast(unsigned, f);
  u += 0x7fffu + ((u >> 16) & 1u);  // RNE
  return (unsigned short)(u >> 16);
}
__device__ __forceinline__ f32x4 mfma16(short8 a, short8 b, f32x4 c) {
  return __builtin_amdgcn_mfma_f32_16x16x32_bf16(a, b, c, 0, 0, 0);
}
__device__ __forceinline__ float rcpf(float x) { return __builtin_amdgcn_rcpf(x); }

// proven R8 elementwise: 5 exp + 3 rcp per unit
__device__ __forceinline__ float lstm_ew(float gi, float gf, float gg, float go, float& c) {
  float ei = __expf(-gi), ef = __expf(-gf), eg = __expf(-2.f * gg);
  float di = 1.f + ei, df = 1.f + ef, dg = 1.f + eg;
  float r1 = rcpf(di * dg);
  float si = r1 * dg;
  float tg = 2.f * (r1 * di) - 1.f;
  c = rcpf(df) * c + si * tg;
  float eo = __expf(-go), ec = __expf(2.f * c);
  float do_ = 1.f + eo, dc = 1.f + ec;
  float r3 = rcpf(do_ * dc);
  float so = r3 * dc;
  float th = 1.f - 2.f * (r3 * do_);
  return so * th;
}

__device__ __forceinline__ short8 cvt8(f32x4 v0, f32x4 v1) {
  short8 o;
  o[0] = (short)f2bf(v0[0]); o[1] = (short)f2bf(v0[1]);
  o[2] = (short)f2bf(v0[2]); o[3] = (short)f2bf(v0[3]);
  o[4] = (short)f2bf(v1[0]); o[5] = (short)f2bf(v1[1]);
  o[6] = (short)f2bf(v1[2]); o[7] = (short)f2bf(v1[3]);
  return o;
}

__device__ __forceinline__ void bar_lds() {  // LDS-only barrier; vmem stays in flight
  asm volatile("s_waitcnt lgkmcnt(0)" ::: "memory");
  __builtin_amdgcn_s_barrier();
}

__device__ __forceinline__ void gload16(const void* g, void* l) {
  __builtin_amdgcn_global_load_lds(
      (const __attribute__((address_space(1))) void*)g,
      (__attribute__((address_space(3))) void*)l, 16, 0, 0);
}

// ---------------- prep: x image in LDS-tile layout (rotation swizzle) --------
// word gid = (bblk*1024 + t)*512 + r*32 + s; slot s holds chunk (s - r) & 31.
__global__ __launch_bounds__(256, 4) void prep_kernel(
    const float* __restrict__ x, const float* __restrict__ mask,
    unsigned short* __restrict__ img) {
  int gid = blockIdx.x * 256 + threadIdx.x;
  int i = gid & 511;
  int tt = (gid >> 9) & 1023;
  int bblk = gid >> 19;
  int r = i >> 5, s = i & 31, kc = (s - r) & 31;
  int b = bblk * 16 + r;
  const f32x4* src = (const f32x4*)(x + ((size_t)b * T_ + tt) * E_ + kc * 8);
  float mk = mask[(size_t)b * T_ + tt];
  ((short8*)img)[gid] = cvt8(src[0] * mk, src[1] * mk);
}

// step body: compile-time parity PAR. Reads HS[PAR], gload->XS[PAR],
// xg reads XS[1-PAR], writes HS[1-PAR], Hbuf parity (1-PAR) via HBW.
#define REC_STEP(PAR, TT, MORE_)                                                \
  {                                                                             \
    const bool more_ = (MORE_);                                                 \
    if constexpr (PREP) {                                                       \
      if ((TT) + 2 < T_) {                                                      \
        gload16(gsrc, (char*)XS[PAR] + w * 1024);                               \
        gsrc += dstep;                                                          \
      }                                                                         \
    }                                                                           \
    f32x4 xv0, xv1;                                                             \
    float mk = 0.f;                                                             \
    if constexpr (!PREP) {                                                      \
      if (more_) {                                                              \
        int ts = d ? (T_ - 2 - (TT)) : ((TT) + 1);                              \
        const f32x4* px = (const f32x4*)(x + ((size_t)gb_s * T_ + ts) * E_ + sc * 8); \
        xv0 = px[0]; xv1 = px[1];                                               \
        mk = mask[(size_t)gb_s * T_ + ts];                                      \
      }                                                                         \
    }                                                                           \
    {                                                                           \
      const char* hsP = (const char*)HS[PAR];                                   \
      _Pragma("unroll") for (int kp = 0; kp < 4; ++kp) {                        \
        short8 b0 = *(const short8*)(hsP + ro[2 * kp]);                         \
        short8 b1 = *(const short8*)(hsP + ro[2 * kp + 1]);                     \
        acc[0] = mfma16(wh[0][2 * kp], b0, acc[0]);                             \
        acc[1] = mfma16(wh[1][2 * kp], b0, acc[1]);                             \
        accB[0] = mfma16(wh[0][2 * kp + 1], b1, accB[0]);                       \
        accB[1] = mfma16(wh[1][2 * kp + 1], b1, accB[1]);                       \
      }                                                                         \
    }                                                                           \
    float h0 = lstm_ew(acc[0][0] + accB[0][0], acc[0][1] + accB[0][1],          \
                       acc[0][2] + accB[0][2], acc[0][3] + accB[0][3], cs[0]);  \
    float h1 = lstm_ew(acc[1][0] + accB[1][0], acc[1][1] + accB[1][1],          \
                       acc[1][2] + accB[1][2], acc[1][3] + accB[1][3], cs[1]);  \
    hsums[0] += h0;                                                             \
    hsums[1] += h1;                                                             \
    if (more_) {                                                                \
      const unsigned tag = (unsigned)((TT) + 1);                                \
      unsigned long long* __restrict__ hb = (PAR) ? Hb0 : Hb1;                  \
      unsigned pay;                                                             \
      asm("v_cvt_pk_bf16_f32 %0, %1, %2" : "=v"(pay) : "v"(h0), "v"(h1));       \
      unsigned long long wrd = (((unsigned long long)tag) << 32) | (unsigned long long)pay; \
      __hip_atomic_store(&hb[pubIdx], wrd, __ATOMIC_RELAXED,                    \
                         __HIP_MEMORY_SCOPE_AGENT);                             \
      asm volatile("" ::: "memory");                                            \
      *(int*)((char*)HS[1 - (PAR)] + ownOff) = (int)pay;                        \
      if constexpr (!PREP) {                                                    \
        ((short8*)XS[1 - (PAR)])[sr * 32 + ((sc + sr) & 31)] = cvt8(xv0 * mk, xv1 * mk); \
        bar_lds();                                                              \
      }                                                                         \
      acc[0] = bias4[0];                                                        \
      acc[1] = bias4[1];                                                        \
      accB[0] = (f32x4){0.f, 0.f, 0.f, 0.f};                                    \
      accB[1] = (f32x4){0.f, 0.f, 0.f, 0.f};                                    \
      {                                                                         \
        const char* xsP = (const char*)XS[1 - (PAR)];                           \
        _Pragma("unroll") for (int kp = 0; kp < 4; ++kp) {                      \
          short8 b0 = *(const short8*)(xsP + ro[2 * kp]);                       \
          short8 b1 = *(const short8*)(xsP + ro[2 * kp + 1]);                   \
          acc[0] = mfma16(wi[0][2 * kp], b0, acc[0]);                           \
          acc[1] = mfma16(wi[1][2 * kp], b0, acc[1]);                           \
          accB[0] = mfma16(wi[0][2 * kp + 1], b1, accB[0]);                     \
          accB[1] = mfma16(wi[1][2 * kp + 1], b1, accB[1]);                     \
        }                                                                       \
      }                                                                         \
      unsigned long long v0 = __hip_atomic_load(&hb[p0], __ATOMIC_RELAXED,      \
                                                __HIP_MEMORY_SCOPE_AGENT);      \
      unsigned long long v1 = __hip_atomic_load(&hb[p1], __ATOMIC_RELAXED,      \
                                                __HIP_MEMORY_SCOPE_AGENT);      \
      unsigned long long v2 = __hip_atomic_load(&hb[p2], __ATOMIC_RELAXED,      \
                                                __HIP_MEMORY_SCOPE_AGENT);      \
      asm volatile("" ::: "memory");                                            \
      while (((unsigned)(v0 >> 32) != tag) | ((unsigned)(v1 >> 32) != tag) |    \
             ((unsigned)(v2 >> 32) != tag)) {                                   \
        if ((unsigned)(v0 >> 32) != tag)                                        \
          v0 = __hip_atomic_load(&hb[p0], __ATOMIC_RELAXED, __HIP_MEMORY_SCOPE_AGENT); \
        if ((unsigned)(v1 >> 32) != tag)                                        \
          v1 = __hip_atomic_load(&hb[p1], __ATOMIC_RELAXED, __HIP_MEMORY_SCOPE_AGENT); \
        if ((unsigned)(v2 >> 32) != tag)                                        \
          v2 = __hip_atomic_load(&hb[p2], __ATOMIC_RELAXED, __HIP_MEMORY_SCOPE_AGENT); \
        asm volatile("" ::: "memory");                                          \
      }                                                                         \
      char* hw = (char*)HS[1 - (PAR)];                                          \
      *(int*)(hw + uo0) = (int)(unsigned)v0;                                    \
      *(int*)(hw + uo1) = (int)(unsigned)v1;                                    \
      *(int*)(hw + uo2) = (int)(unsigned)v2;                                    \
      bar_lds();                                                                \
    }                                                                           \
  }

// ---------------- rec: fused projection + recurrence --------------------------
// grid 64, 512 threads. g = bid & 15, m = bid >> 4. Member m owns units [m*64,+64).
template <bool PREP>
__global__ __launch_bounds__(512, 1) void rec_kernel(
    const float* __restrict__ x, const float* __restrict__ mask,
    const unsigned short* __restrict__ img,
    const float* __restrict__ WihF, const float* __restrict__ WhhF,
    const float* __restrict__ bF, const float* __restrict__ WihB,
    const float* __restrict__ WhhB, const float* __restrict__ bB,
    unsigned long long* __restrict__ Hbuf, float* __restrict__ hsum) {
  __shared__ __align__(16) short XS[2][16 * 256];  // x stage, parity dbuf (16KB)
  __shared__ __align__(16) short HS[2][16 * 256];  // h stage, parity dbuf (16KB)

  const int bid = blockIdx.x;
  const int g = bid & 15, m = bid >> 4;
  const int d = g >> 3, bblk = g & 7;
  const int tid = threadIdx.x;
  const int w = tid >> 6, l = tid & 63, l15 = l & 15, l4 = l >> 4;
  const int sr = tid >> 5, sc = tid & 31;  // fallback staging row/chunk
  const int gb_s = bblk * 16 + sr;

  const float* Wih = d ? WihB : WihF;
  const float* Whh = d ? WhhB : WhhF;
  const float* bias = d ? bB : bF;

  // ---- weight A-fragments -> registers (R13 row map) ----
  short8 wi[2][8], wh[2][8];
#pragma unroll
  for (int i = 0; i < 2; ++i) {
    int u_row = w * 8 + (l15 >> 2) * 2 + i;
    size_t nat = (size_t)((l15 & 3) * 256 + m * 64 + u_row);
#pragma unroll
    for (int kb = 0; kb < 8; ++kb) {
      const f32x4* pi = (const f32x4*)(Wih + nat * E_ + kb * 32 + l4 * 8);
      wi[i][kb] = cvt8(pi[0], pi[1]);
      const f32x4* ph = (const f32x4*)(Whh + nat * H_ + kb * 32 + l4 * 8);
      wh[i][kb] = cvt8(ph[0], ph[1]);
    }
  }
  f32x4 bias4[2];
#pragma unroll
  for (int i = 0; i < 2; ++i)
#pragma unroll
    for (int r = 0; r < 4; ++r)
      bias4[i][r] = bias[r * 256 + m * 64 + w * 8 + l4 * 2 + i];

  // ---- precomputed lane constants ----
  // B-operand byte offsets, rotation swizzle: off(c) = l15*512 + ((c+l15)&31)*16
  int ro[8];
#pragma unroll
  for (int kp = 0; kp < 4; ++kp) {
    ro[2 * kp] = l15 * 512 + ((((kp * 8 + l4) + l15) & 31) << 4);
    ro[2 * kp + 1] = l15 * 512 + ((((kp * 8 + 4 + l4) + l15) & 31) << 4);
  }
  // publish word index (uw = m*32+w*4+l4, batch-minor -> coalesced)
  const int pubIdx = (m * 32 + w * 4 + l4) * 16 + l15;
  // own HS byte offset: unit chunk c = m*8+w, batch l15, sub l4*4
  const int ownOff = l15 * 512 + ((((m * 8 + w) + l15) & 31) << 4) + l4 * 4;
  // poll phys words (3/thread, skip own member's 512-block)
  int pp = tid * 3;
  const int p0 = pp + (pp >= m * 512 ? 512 : 0);
  const int p1 = pp + 1 + (pp + 1 >= m * 512 ? 512 : 0);
  const int p2 = pp + 2 + (pp + 2 >= m * 512 ? 512 : 0);
  // unpack byte offsets: word p = uw*16+b -> HS[b], chunk uw>>2, sub (uw&3)*4
#define UOFF(p) (((p) & 15) * 512 + (((((p) >> 6) + ((p) & 15)) & 31) << 4) + ((((p) >> 4) & 3) * 4))
  const int uo0 = UOFF(p0), uo1 = UOFF(p1), uo2 = UOFF(p2);
#undef UOFF
  // Hbuf parity bases
  unsigned long long* __restrict__ Hb0 = Hbuf + ((size_t)g * 2 + 0) * 2048;
  unsigned long long* __restrict__ Hb1 = Hbuf + ((size_t)g * 2 + 1) * 2048;

  // x image source pointer; one 8KB tile per t
  const int dstep = d ? -8192 : 8192;
  const char* gsrc = (const char*)img +
      ((size_t)(bblk * 1024 + (d ? (T_ - 1) : 0)) * 8192) + (size_t)tid * 16;

  // ---- prologue: HS[0]=0; stage x_0 (and x_1); acc = bias + xg_0 ----
  ((int4*)HS)[tid] = (int4){0, 0, 0, 0};  // zeros HS[0]
  if constexpr (PREP) {
    gload16(gsrc, (char*)XS[0] + w * 1024);
    gload16(gsrc + dstep, (char*)XS[1] + w * 1024);
    gsrc += 2 * dstep;
  } else {
    int ts = d ? (T_ - 1) : 0;
    const f32x4* px = (const f32x4*)(x + ((size_t)gb_s * T_ + ts) * E_ + sc * 8);
    float mk = mask[(size_t)gb_s * T_ + ts];
    ((short8*)XS[0])[sr * 32 + ((sc + sr) & 31)] = cvt8(px[0] * mk, px[1] * mk);
  }
  __syncthreads();  // drains gloads + HS[0] zeros visible

  f32x4 acc[2], accB[2];
  acc[0] = bias4[0];
  acc[1] = bias4[1];
  accB[0] = (f32x4){0.f, 0.f, 0.f, 0.f};
  accB[1] = (f32x4){0.f, 0.f, 0.f, 0.f};
  {
    const char* xsP = (const char*)XS[0];
#pragma unroll
    for (int kp = 0; kp < 4; ++kp) {
      short8 b0 = *(const short8*)(xsP + ro[2 * kp]);
      short8 b1 = *(const short8*)(xsP + ro[2 * kp + 1]);
      acc[0] = mfma16(wi[0][2 * kp], b0, acc[0]);
      acc[1] = mfma16(wi[1][2 * kp], b0, acc[1]);
      accB[0] = mfma16(wi[0][2 * kp + 1], b1, accB[0]);
      accB[1] = mfma16(wi[1][2 * kp + 1], b1, accB[1]);
    }
  }
  __syncthreads();  // XS[0] consumed before first in-loop gload overwrites it

  float cs[2] = {0.f, 0.f};
  float hsums[2] = {0.f, 0.f};

  for (int t2 = 0; t2 < 511; ++t2) {
    const int tt = t2 * 2;
    REC_STEP(0, tt, true);
    REC_STEP(1, tt + 1, true);
  }
  REC_STEP(0, 1022, true);
  REC_STEP(1, 1023, false);

  // pooled sums: lane owns (batch bblk*16+l15, units gu, gu+1) — 8B store
  {
    int gb_t = bblk * 16 + l15;
    int gu = m * 64 + w * 8 + l4 * 2;
    *(f32x2*)(hsum + ((size_t)d * B_ + gb_t) * H_ + gu) = (f32x2){hsums[0], hsums[1]};
  }
}

// ---------------- head: linear ----------------------------------------------
__global__ __launch_bounds__(256, 1) void head_kernel(
    const float* __restrict__ hsum, const float* __restrict__ Wlin,
    const float* __restrict__ blin, float* __restrict__ out) {
  int tid = threadIdx.x;  // 256 = 128 b x 2 c
  int b = tid >> 1, c = tid & 1;
  const f32x4* hf = (const f32x4*)(hsum + (size_t)b * H_);
  const f32x4* hbk = (const f32x4*)(hsum + (size_t)B_ * H_ + (size_t)b * H_);
  const f32x4* wl = (const f32x4*)(Wlin + (size_t)c * 512);
  float s = 0.f;
  for (int j = 0; j < 64; ++j) {
    f32x4 a = hf[j], ww = wl[j];
    s += a[0] * ww[0] + a[1] * ww[1] + a[2] * ww[2] + a[3] * ww[3];
  }
  for (int j = 0; j < 64; ++j) {
    f32x4 a = hbk[j], ww = wl[64 + j];
    s += a[0] * ww[0] + a[1] * ww[1] + a[2] * ww[2] + a[3] * ww[3];
  }
  out[tid] = s * (1.0f / 1024.0f) + blin[c];
}

// ---------------- launch -----------------------------------------------------
extern "C" void kernel_launch(void* const* d_in, const int* in_sizes, int n_in,
                              void* d_out, int out_size, void* d_ws, size_t ws_size,
                              hipStream_t stream) {
  const float* emb = (const float*)d_in[0];
  const float* mask = (const float*)d_in[1];
  const float* Wih_f = (const float*)d_in[2];
  const float* Whh_f = (const float*)d_in[3];
  const float* b_f = (const float*)d_in[4];
  const float* Wih_b = (const float*)d_in[5];
  const float* Whh_b = (const float*)d_in[6];
  const float* b_b = (const float*)d_in[7];
  const float* Wlin = (const float*)d_in[8];
  const float* blin = (const float*)d_in[9];
  float* out = (float*)d_out;

  const size_t HBUF_BYTES = (size_t)16 * 2 * 2048 * 8;      // 512 KiB
  const size_t HSUM_BYTES = (size_t)2 * B_ * H_ * 4;        // 256 KiB
  const size_t IMG_BYTES = (size_t)8 * 1024 * 512 * 16;     // 64 MiB
  if (ws_size < HBUF_BYTES + HSUM_BYTES) return;
  const bool prep = ws_size >= HBUF_BYTES + HSUM_BYTES + IMG_BYTES;

  char* ws = (char*)d_ws;
  unsigned long long* Hbuf = (unsigned long long*)ws;
  float* hsum = (float*)(ws + HBUF_BYTES);
  unsigned short* img = (unsigned short*)(ws + HBUF_BYTES + HSUM_BYTES);

  (void)hipMemsetAsync(Hbuf, 0, HBUF_BYTES, stream);  // tags start at 1; replay-safe
  if (prep) {
    prep_kernel<<<16384, 256, 0, stream>>>(emb, mask, img);
    rec_kernel<true><<<64, 512, 0, stream>>>(emb, mask, img, Wih_f, Whh_f, b_f,
                                             Wih_b, Whh_b, b_b, Hbuf, hsum);
  } else {
    rec_kernel<false><<<64, 512, 0, stream>>>(emb, mask, img, Wih_f, Whh_f, b_f,
                                              Wih_b, Whh_b, b_b, Hbuf, hsum);
  }
  head_kernel<<<1, 256, 0, stream>>>(hsum, Wlin, blin, out);
}